// Round 18
// baseline (474.027 us; speedup 1.0000x reference)
//
#include <hip/hip_runtime.h>

#define NN 10000
#define EE 80000
#define DD 32
#define DEDGE 16
#define LL 3
#define D2V 1024
#define NTILE 2500  // EE/32
#define NWIN 1250   // fused-layer blocks, 64 positions / 2 tiles each

typedef __attribute__((ext_vector_type(8))) short short8v;
typedef __attribute__((ext_vector_type(16))) float f32x16;

__device__ __forceinline__ unsigned short bf16rne(float x) {
    unsigned u = __float_as_uint(x);
    return (unsigned short)((u + 0x7FFF + ((u >> 16) & 1)) >> 16);
}
__device__ __forceinline__ float bf16tof(unsigned short h) {
    return __uint_as_float(((unsigned)h) << 16);
}
__device__ __forceinline__ uint4 pack8(const unsigned short* u) {
    uint4 r;
    r.x = (unsigned)u[0] | ((unsigned)u[1] << 16);
    r.y = (unsigned)u[2] | ((unsigned)u[3] << 16);
    r.z = (unsigned)u[4] | ((unsigned)u[5] << 16);
    r.w = (unsigned)u[6] | ((unsigned)u[7] << 16);
    return r;
}

// ---------------- zero kernel ----------------
__global__ __launch_bounds__(256) void zero_kernel(int* __restrict__ p, int n) {
    const int i = blockIdx.x * 256 + threadIdx.x;
    if (i < n) p[i] = 0;
}

// ---------------- S1: wide merged setup (R13-proven) ----------------
__global__ __launch_bounds__(256) void setup1_kernel(
    const int* __restrict__ ei,
    const float* __restrict__ w, const float* __restrict__ wb,
    const float* __restrict__ lg, const float* __restrict__ lb,
    int* __restrict__ cnt, float* __restrict__ st,
    uint4* __restrict__ afh, uint4* __restrict__ afl, uint4* __restrict__ a2f) {
    const int bid = blockIdx.x;
    const int t = threadIdx.x;
    if (bid < 313) {
        const int e = bid * 256 + t;
        if (e < EE) atomicAdd(&cnt[ei[EE + e]], 1);
    } else if (bid < 377) {
        const int r0 = (bid - 313) * 16;
        const int k = t >> 4, j = t & 15;
        float acc = 0.f;
#pragma unroll
        for (int r = 0; r < 16; ++r)
            acc = fmaf(w[(r0 + r) * DEDGE + k], w[(r0 + r) * DEDGE + j], acc);
        atomicAdd(&st[t], acc * (1.f / D2V));
        if (t < DEDGE) {
            float s = 0.f, q = 0.f;
#pragma unroll
            for (int r = 0; r < 16; ++r) {
                s += w[(r0 + r) * DEDGE + t];
                q = fmaf(wb[r0 + r], w[(r0 + r) * DEDGE + t], q);
            }
            atomicAdd(&st[256 + t], s * (1.f / D2V));
            atomicAdd(&st[272 + t], q * (1.f / D2V));
        } else if (t == 16) {
            float s = 0.f, s2 = 0.f;
#pragma unroll
            for (int r = 0; r < 16; ++r) {
                s += wb[r0 + r];
                s2 = fmaf(wb[r0 + r], wb[r0 + r], s2);
            }
            atomicAdd(&st[288], s * (1.f / D2V));
            atomicAdd(&st[289], s2 * (1.f / D2V));
        }
    } else {
        const int tid = (bid - 377) * 256 + t;
        if (tid >= 32 * 64) return;
        const int d = tid >> 6, l = tid & 63;
        const int row = l & 31, kh = l >> 5;
        const int r = d * 32 + row;
        const float g = lg[r];
        unsigned short uh[8], ul[8];
#pragma unroll
        for (int i = 0; i < 8; ++i) {
            const float v = g * w[r * DEDGE + kh * 8 + i];
            const unsigned short h = bf16rne(v);
            uh[i] = h;
            ul[i] = bf16rne(v - bf16tof(h));
        }
        afh[d * 64 + l] = pack8(uh);
        afl[d * 64 + l] = pack8(ul);
        if (kh == 0) {
            const float bg = g * wb[r];
            const float lbv = lb[r];
            const unsigned short bgh = bf16rne(bg);
            const unsigned short bgl = bf16rne(bg - bf16tof(bgh));
            const unsigned short gh = bf16rne(g);
            const unsigned short gl = bf16rne(g - bf16tof(gh));
            const unsigned short lbh = bf16rne(lbv);
            const unsigned short lbl = bf16rne(lbv - bf16tof(lbh));
            unsigned short sarr[8] = {bgh, bgl, bgh, gh, gl, gh, lbh, lbl};
            a2f[d * 64 + l] = pack8(sarr);
        } else {
            a2f[d * 64 + l] = make_uint4(0, 0, 0, 0);
        }
    }
}

// ---------------- scan + per-window node-range precompute (1251 windows) ----------------
__global__ __launch_bounds__(1024) void scan_kernel(int* __restrict__ cur, int* __restrict__ off,
                                                    int* __restrict__ nfarr) {
    __shared__ int s[1024];
    const int t = threadIdx.x;
    const int base = t * 10;
    int loc[10];
    int run = 0;
#pragma unroll
    for (int i = 0; i < 10; ++i) {
        const int idx = base + i;
        const int v = (idx < NN) ? cur[idx] : 0;
        loc[i] = run;
        run += v;
    }
    s[t] = run;
    __syncthreads();
    for (int o = 1; o < 1024; o <<= 1) {
        const int v = (t >= o) ? s[t - o] : 0;
        __syncthreads();
        s[t] += v;
        __syncthreads();
    }
    const int excl = s[t] - run;
#pragma unroll
    for (int i = 0; i < 10; ++i) {
        const int idx = base + i;
        if (idx < NN) {
            off[idx] = excl + loc[i];
            cur[idx] = excl + loc[i];
        }
    }
    if (t == 1023) off[NN] = s[1023];
    __syncthreads();
    // nfarr[b] = first node n with off[n] >= 64*b, b = 0..NWIN
    for (int b = t; b <= NWIN; b += 1024) {
        const int target = b * 64;
        int lo = 0, hi = NN;
        while (lo < hi) {
            const int mid = (lo + hi) >> 1;
            if (off[mid] < target) lo = mid + 1; else hi = mid;
        }
        nfarr[b] = lo;
    }
}

// ---------------- S2: scatter rank + per-edge LN stats + B-fragments ----------------
__global__ __launch_bounds__(256) void stats_edge_perm2(const float* __restrict__ eattr,
                                                        const float* __restrict__ st,
                                                        const int* __restrict__ ei,
                                                        int* __restrict__ cur,
                                                        uint4* __restrict__ bfh,
                                                        uint4* __restrict__ bfl,
                                                        uint4* __restrict__ b2f,
                                                        int* __restrict__ sperm) {
    const int e = blockIdx.x * 256 + threadIdx.x;
    if (e >= EE) return;
    const int tgt = ei[EE + e];
    const int p = atomicAdd(&cur[tgt], 1);
    sperm[p] = ei[e];
    float ea[16];
    {
        const float4* ep = (const float4*)(eattr + e * DEDGE);
#pragma unroll
        for (int c = 0; c < 4; ++c) {
            const float4 t4 = ep[c];
            ea[4 * c] = t4.x; ea[4 * c + 1] = t4.y; ea[4 * c + 2] = t4.z; ea[4 * c + 3] = t4.w;
        }
    }
    float m = st[288];
#pragma unroll
    for (int k = 0; k < 16; ++k) m = fmaf(st[256 + k], ea[k], m);
    float ex2 = st[289];
#pragma unroll
    for (int k = 0; k < 16; ++k) {
        float tv = 2.f * st[272 + k];
#pragma unroll
        for (int j = 0; j < 16; ++j) tv = fmaf(st[k * 16 + j], ea[j], tv);
        ex2 = fmaf(tv, ea[k], ex2);
    }
    const float var = fmaxf(ex2 - m * m, 0.f);
    const float inv = rsqrtf(var + 1e-5f);
    const float nmi = -m * inv;
    const int tt = p >> 5, col = p & 31;
#pragma unroll
    for (int h = 0; h < 2; ++h) {
        unsigned short uh[8], ul[8];
#pragma unroll
        for (int i = 0; i < 8; ++i) {
            const float v = inv * ea[8 * h + i];
            const unsigned short a = bf16rne(v);
            uh[i] = a;
            ul[i] = bf16rne(v - bf16tof(a));
        }
        bfh[tt * 64 + h * 32 + col] = pack8(uh);
        bfl[tt * 64 + h * 32 + col] = pack8(ul);
    }
    const unsigned short ivh = bf16rne(inv);
    const unsigned short ivl = bf16rne(inv - bf16tof(ivh));
    const unsigned short nmh = bf16rne(nmi);
    const unsigned short nml = bf16rne(nmi - bf16tof(nmh));
    const unsigned short one = 0x3F80;
    unsigned short s[8] = {ivh, ivh, ivl, nmh, nmh, nml, one, one};
    b2f[tt * 64 + col] = pack8(s);
    b2f[tt * 64 + 32 + col] = make_uint4(0, 0, 0, 0);
}

// ---------------- fused layer v3: d-split wave pairs, no big LDS, high occupancy ----------------
// 256 threads = 4 waves = 2 groups. Group g computes tile b*2+g: sub s does d in [16s,16s+16),
// partials combined via LDS (r-major, conflict-free). Spill tiles (block-uniform count <= 2)
// cover owned nodes whose edges extend past the window. A-frags read from L2 (R5-proven).
template <bool FUSE>
__global__ __launch_bounds__(256, 4) void fused_layer(
    const float* __restrict__ x, const int* __restrict__ sperm, const int* __restrict__ off,
    const int* __restrict__ nfarr,
    const uint4* __restrict__ afh, const uint4* __restrict__ afl, const uint4* __restrict__ a2f,
    const uint4* __restrict__ bfh, const uint4* __restrict__ bfl, const uint4* __restrict__ b2f,
    float* __restrict__ msg,
    const float* __restrict__ root_w, const float* __restrict__ conv_b,
    const float* __restrict__ res_w, const float* __restrict__ res_b,
    const float* __restrict__ lng, const float* __restrict__ lnb,
    const float* __restrict__ o0, const float* __restrict__ o1,
    const float* __restrict__ fw, const float* __restrict__ fb,
    const float* __restrict__ fg, const float* __restrict__ fbb,
    float* __restrict__ out) {
    __shared__ float pm[2][16 * 64];   // 8 KB partial-sum buffers (r-major)
    __shared__ float fwl[32 * 97];     // 12.4 KB fuse weights (stride-97, conflict-free)
    const int t = threadIdx.x;
    const int wv = t >> 6, lane = t & 63;
    const int g = wv >> 1, s = wv & 1;
    const int col = lane & 31, hi2 = lane >> 5;
    const int b = blockIdx.x;

    if (FUSE) {
        for (int i = t; i < 32 * 96; i += 256) fwl[(i / 96) * 97 + (i % 96)] = fw[i];
    }

    const int nf = nfarr[b];
    const int nl = nfarr[b + 1];
    const int p1 = (b + 1) * 64;
    int spill = (off[nl] + 31) / 32 - (p1 >> 5);
    spill = spill < 0 ? 0 : (spill > 2 ? 2 : spill);

    // computes this sub's d-half partial for tile w into mg[16]
    auto tilePartial = [&](int w, float* mg) {
        const int p = w * 32 + col;
        const int si = sperm[p];
        float xr[16];
        {
            const float4* xp = (const float4*)(x + si * DD + s * 16);
#pragma unroll
            for (int c = 0; c < 4; ++c) {
                const float4 t4 = xp[c];
                xr[4 * c] = t4.x; xr[4 * c + 1] = t4.y;
                xr[4 * c + 2] = t4.z; xr[4 * c + 3] = t4.w;
            }
        }
        const short8v bh = ((const short8v*)bfh)[w * 64 + lane];
        const short8v bl = ((const short8v*)bfl)[w * 64 + lane];
        const short8v b2 = ((const short8v*)b2f)[w * 64 + lane];
#pragma unroll
        for (int i = 0; i < 16; ++i) mg[i] = 0.f;
#pragma unroll
        for (int dd = 0; dd < 16; ++dd) {
            const int d = s * 16 + dd;
            const short8v ah = ((const short8v*)afh)[d * 64 + lane];
            const short8v al = ((const short8v*)afl)[d * 64 + lane];
            const short8v a2 = ((const short8v*)a2f)[d * 64 + lane];
            f32x16 C;
#pragma unroll
            for (int r = 0; r < 16; ++r) C[r] = 0.f;
            C = __builtin_amdgcn_mfma_f32_32x32x16_bf16(ah, bh, C, 0, 0, 0);
            C = __builtin_amdgcn_mfma_f32_32x32x16_bf16(ah, bl, C, 0, 0, 0);
            C = __builtin_amdgcn_mfma_f32_32x32x16_bf16(al, bh, C, 0, 0, 0);
            C = __builtin_amdgcn_mfma_f32_32x32x16_bf16(a2, b2, C, 0, 0, 0);
            const float xd = xr[dd];
#pragma unroll
            for (int r = 0; r < 16; ++r) mg[r] = fmaf(xd, fmaxf(C[r], 0.f), mg[r]);
        }
    };
    auto combineStore = [&](int w, float* mg) {
        // sub1's partial is in pm[g]; sub0 adds and stores
        const int p = w * 32 + col;
#pragma unroll
        for (int r = 0; r < 16; ++r) mg[r] += pm[g][r * 64 + lane];
        float* op = msg + p * DD + hi2 * 4;
#pragma unroll
        for (int q = 0; q < 4; ++q)
            *(float4*)(op + q * 8) =
                make_float4(mg[4 * q], mg[4 * q + 1], mg[4 * q + 2], mg[4 * q + 3]);
    };

    {
        float mg[16];
        const int T = b * 2 + g;
        tilePartial(T, mg);
        if (s == 1) {
#pragma unroll
            for (int r = 0; r < 16; ++r) pm[g][r * 64 + lane] = mg[r];
        }
        __syncthreads();
        if (s == 0) combineStore(T, mg);
    }
    if (spill > 0) {
        __syncthreads();  // protect pm reuse
        float mg[16];
        const bool act = (g < spill);
        const int T2 = b * 2 + 2 + g;
        if (act && T2 < NTILE) tilePartial(T2, mg);
        if (act && T2 < NTILE && s == 1) {
#pragma unroll
            for (int r = 0; r < 16; ++r) pm[g][r * 64 + lane] = mg[r];
        }
        __syncthreads();
        if (act && T2 < NTILE && s == 0) combineStore(T2, mg);
    }
    __syncthreads();  // drains vmcnt -> all block msg stores visible to this block

    // ---- node phase: owned nodes [nf, nl), 8 half-waves, stride 8 ----
    const int f = col;
    float wrow[32];
    {
        const float4* rp = (const float4*)(root_w + f * DD);
        const float4* sp = (const float4*)(res_w + f * DD);
#pragma unroll
        for (int c = 0; c < 8; ++c) {
            const float4 a = rp[c];
            const float4 bb4 = sp[c];
            wrow[4 * c] = a.x + bb4.x; wrow[4 * c + 1] = a.y + bb4.y;
            wrow[4 * c + 2] = a.z + bb4.z; wrow[4 * c + 3] = a.w + bb4.w;
        }
    }
    const float bias = conv_b[f] + res_b[f];
    const float gg = lng[f], bb = lnb[f];
    float fbv = 0.f, fgv = 0.f, fbbv = 0.f;
    if (FUSE) { fbv = fb[f]; fgv = fg[f]; fbbv = fbb[f]; }
    for (int n = nf + (wv * 2 + hi2); n < nl; n += 8) {
        float acc = bias;
        const int k0 = off[n], k1 = off[n + 1];
        for (int k = k0; k < k1; ++k) acc += msg[k * DD + f];
        const float xl = x[n * DD + f];
#pragma unroll
        for (int d = 0; d < DD; ++d) acc = fmaf(__shfl(xl, hi2 * 32 + d), wrow[d], acc);
        float s1 = acc, s2 = acc * acc;
#pragma unroll
        for (int o = 16; o >= 1; o >>= 1) {
            s1 += __shfl_xor(s1, o);
            s2 += __shfl_xor(s2, o);
        }
        const float m = s1 * (1.f / 32.f);
        const float v = s2 * (1.f / 32.f) - m * m;
        const float inv = rsqrtf(v + 1e-5f);
        const float o2v = fmaf((acc - m) * inv, gg, bb);
        if (!FUSE) {
            out[n * DD + f] = o2v;
        } else {
            float fa = fbv;
            const float c0 = o0[n * DD + f], c1 = o1[n * DD + f];
            const float* fr = fwl + f * 97;
#pragma unroll
            for (int d = 0; d < DD; ++d) fa = fmaf(__shfl(c0, hi2 * 32 + d), fr[d], fa);
#pragma unroll
            for (int d = 0; d < DD; ++d) fa = fmaf(__shfl(c1, hi2 * 32 + d), fr[32 + d], fa);
#pragma unroll
            for (int d = 0; d < DD; ++d) fa = fmaf(__shfl(o2v, hi2 * 32 + d), fr[64 + d], fa);
            float t1 = fa, t2 = fa * fa;
#pragma unroll
            for (int o = 16; o >= 1; o >>= 1) {
                t1 += __shfl_xor(t1, o);
                t2 += __shfl_xor(t2, o);
            }
            const float fm = t1 * (1.f / 32.f);
            const float fv = t2 * (1.f / 32.f) - fm * fm;
            const float fi = rsqrtf(fv + 1e-5f);
            out[n * DD + f] = fmaxf(fmaf((fa - fm) * fi, fgv, fbbv), 0.f);
        }
    }
}

extern "C" void kernel_launch(void* const* d_in, const int* in_sizes, int n_in,
                              void* d_out, int out_size, void* d_ws, size_t ws_size,
                              hipStream_t stream) {
    const float* x   = (const float*)d_in[0];
    const int*   ei  = (const int*)d_in[1];
    const float* ea  = (const float*)d_in[2];
    const float* emw = (const float*)d_in[3];
    const float* emb = (const float*)d_in[4];
    const float* elg = (const float*)d_in[5];
    const float* elb = (const float*)d_in[6];
    const float* rootw = (const float*)d_in[7];
    const float* convb = (const float*)d_in[8];
    const float* resw  = (const float*)d_in[9];
    const float* resb  = (const float*)d_in[10];
    const float* lng   = (const float*)d_in[11];
    const float* lnb   = (const float*)d_in[12];
    const float* fw    = (const float*)d_in[13];
    const float* fb    = (const float*)d_in[14];
    const float* flg   = (const float*)d_in[15];
    const float* flb   = (const float*)d_in[16];
    float* doutp = (float*)d_out;

    // layout: uint4 frags | msg | out0 | out1 | st | cur | off | nfarr(1280) | sperm
    const size_t U4N = 2048 * 3 + (size_t)NTILE * 64 * 3;
    const size_t FR0 = U4N * 4;
    const size_t FTOT = FR0 + (size_t)EE * DD + 2 * (size_t)NN * DD + 320;
    const size_t ITOT = 2 * (NN + 1) + 1280 + (size_t)EE;
    const size_t PRIMARY_NEED = FTOT * 4 + ITOT * 4 + 256;

    if (ws_size < PRIMARY_NEED) return;  // harness provides ample workspace

    uint4* u4 = (uint4*)d_ws;
    uint4* afh = u4;
    uint4* afl = afh + 2048;
    uint4* a2f = afl + 2048;
    uint4* bfh = a2f + 2048;
    uint4* bfl = bfh + (size_t)NTILE * 64;
    uint4* b2f = bfl + (size_t)NTILE * 64;
    float* wsf = (float*)d_ws;
    float* msg  = wsf + FR0;
    float* out0 = msg + (size_t)EE * DD;
    float* out1 = out0 + NN * DD;
    float* st   = out1 + NN * DD;
    int* cur   = (int*)(st + 320);
    int* off   = cur + (NN + 1);
    int* nfarr = off + (NN + 1);
    int* sperm = nfarr + 1280;

    // setup chain (4 dispatches, R13-proven)
    zero_kernel<<<41, 256, 0, stream>>>((int*)st, 320 + NN + 1);
    setup1_kernel<<<385, 256, 0, stream>>>(ei, emw, emb, elg, elb, cur, st, afh, afl, a2f);
    scan_kernel<<<1, 1024, 0, stream>>>(cur, off, nfarr);
    stats_edge_perm2<<<313, 256, 0, stream>>>(ea, st, ei, cur, bfh, bfl, b2f, sperm);

    // fused layers (3 dispatches)
    fused_layer<false><<<NWIN, 256, 0, stream>>>(x, sperm, off, nfarr,
        afh, afl, a2f, bfh, bfl, b2f,
        msg, rootw, convb, resw, resb, lng, lnb,
        nullptr, nullptr, nullptr, nullptr, nullptr, nullptr, out0);
    fused_layer<false><<<NWIN, 256, 0, stream>>>(out0, sperm, off, nfarr,
        afh, afl, a2f, bfh, bfl, b2f,
        msg, rootw + D2V, convb + DD, resw + D2V, resb + DD, lng + DD, lnb + DD,
        nullptr, nullptr, nullptr, nullptr, nullptr, nullptr, out1);
    fused_layer<true><<<NWIN, 256, 0, stream>>>(out1, sperm, off, nfarr,
        afh, afl, a2f, bfh, bfl, b2f,
        msg, rootw + 2 * D2V, convb + 2 * DD, resw + 2 * D2V, resb + 2 * DD,
        lng + 2 * DD, lnb + 2 * DD,
        out0, out1, fw, fb, flg, flb, doutp);
}

// Round 19
// 153.460 us; speedup vs baseline: 3.0889x; 3.0889x over previous
//
#include <hip/hip_runtime.h>

#define NN 10000
#define EE 80000
#define DD 32
#define DEDGE 16
#define LL 3
#define D2V 1024
#define NTILE 2500  // EE/32

typedef __attribute__((ext_vector_type(8))) short short8v;
typedef __attribute__((ext_vector_type(16))) float f32x16;

__device__ __forceinline__ unsigned short bf16rne(float x) {
    unsigned u = __float_as_uint(x);
    return (unsigned short)((u + 0x7FFF + ((u >> 16) & 1)) >> 16);
}
__device__ __forceinline__ float bf16tof(unsigned short h) {
    return __uint_as_float(((unsigned)h) << 16);
}
__device__ __forceinline__ uint4 pack8(const unsigned short* u) {
    uint4 r;
    r.x = (unsigned)u[0] | ((unsigned)u[1] << 16);
    r.y = (unsigned)u[2] | ((unsigned)u[3] << 16);
    r.z = (unsigned)u[4] | ((unsigned)u[5] << 16);
    r.w = (unsigned)u[6] | ((unsigned)u[7] << 16);
    return r;
}

// ---------------- zero kernel ----------------
__global__ __launch_bounds__(256) void zero_kernel(int* __restrict__ p, int n) {
    const int i = blockIdx.x * 256 + threadIdx.x;
    if (i < n) p[i] = 0;
}

// ---------------- S1: wide merged setup (R13-proven) ----------------
__global__ __launch_bounds__(256) void setup1_kernel(
    const int* __restrict__ ei,
    const float* __restrict__ w, const float* __restrict__ wb,
    const float* __restrict__ lg, const float* __restrict__ lb,
    int* __restrict__ cnt, float* __restrict__ st,
    uint4* __restrict__ afh, uint4* __restrict__ afl, uint4* __restrict__ a2f) {
    const int bid = blockIdx.x;
    const int t = threadIdx.x;
    if (bid < 313) {
        const int e = bid * 256 + t;
        if (e < EE) atomicAdd(&cnt[ei[EE + e]], 1);
    } else if (bid < 377) {
        const int r0 = (bid - 313) * 16;
        const int k = t >> 4, j = t & 15;
        float acc = 0.f;
#pragma unroll
        for (int r = 0; r < 16; ++r)
            acc = fmaf(w[(r0 + r) * DEDGE + k], w[(r0 + r) * DEDGE + j], acc);
        atomicAdd(&st[t], acc * (1.f / D2V));
        if (t < DEDGE) {
            float s = 0.f, q = 0.f;
#pragma unroll
            for (int r = 0; r < 16; ++r) {
                s += w[(r0 + r) * DEDGE + t];
                q = fmaf(wb[r0 + r], w[(r0 + r) * DEDGE + t], q);
            }
            atomicAdd(&st[256 + t], s * (1.f / D2V));
            atomicAdd(&st[272 + t], q * (1.f / D2V));
        } else if (t == 16) {
            float s = 0.f, s2 = 0.f;
#pragma unroll
            for (int r = 0; r < 16; ++r) {
                s += wb[r0 + r];
                s2 = fmaf(wb[r0 + r], wb[r0 + r], s2);
            }
            atomicAdd(&st[288], s * (1.f / D2V));
            atomicAdd(&st[289], s2 * (1.f / D2V));
        }
    } else {
        const int tid = (bid - 377) * 256 + t;
        if (tid >= 32 * 64) return;
        const int d = tid >> 6, l = tid & 63;
        const int row = l & 31, kh = l >> 5;
        const int r = d * 32 + row;
        const float g = lg[r];
        unsigned short uh[8], ul[8];
#pragma unroll
        for (int i = 0; i < 8; ++i) {
            const float v = g * w[r * DEDGE + kh * 8 + i];
            const unsigned short h = bf16rne(v);
            uh[i] = h;
            ul[i] = bf16rne(v - bf16tof(h));
        }
        afh[d * 64 + l] = pack8(uh);
        afl[d * 64 + l] = pack8(ul);
        if (kh == 0) {
            const float bg = g * wb[r];
            const float lbv = lb[r];
            const unsigned short bgh = bf16rne(bg);
            const unsigned short bgl = bf16rne(bg - bf16tof(bgh));
            const unsigned short gh = bf16rne(g);
            const unsigned short gl = bf16rne(g - bf16tof(gh));
            const unsigned short lbh = bf16rne(lbv);
            const unsigned short lbl = bf16rne(lbv - bf16tof(lbh));
            unsigned short sarr[8] = {bgh, bgl, bgh, gh, gl, gh, lbh, lbl};
            a2f[d * 64 + l] = pack8(sarr);
        } else {
            a2f[d * 64 + l] = make_uint4(0, 0, 0, 0);
        }
    }
}

__global__ __launch_bounds__(1024) void scan_kernel(int* __restrict__ cur, int* __restrict__ off) {
    __shared__ int s[1024];
    const int t = threadIdx.x;
    const int base = t * 10;
    int loc[10];
    int run = 0;
#pragma unroll
    for (int i = 0; i < 10; ++i) {
        const int idx = base + i;
        const int v = (idx < NN) ? cur[idx] : 0;
        loc[i] = run;
        run += v;
    }
    s[t] = run;
    __syncthreads();
    for (int o = 1; o < 1024; o <<= 1) {
        const int v = (t >= o) ? s[t - o] : 0;
        __syncthreads();
        s[t] += v;
        __syncthreads();
    }
    const int excl = s[t] - run;
#pragma unroll
    for (int i = 0; i < 10; ++i) {
        const int idx = base + i;
        if (idx < NN) {
            off[idx] = excl + loc[i];
            cur[idx] = excl + loc[i];
        }
    }
    if (t == 1023) off[NN] = s[1023];
}

// ---------------- S2: scatter rank + per-edge LN stats + B-fragments ----------------
__global__ __launch_bounds__(256) void stats_edge_perm2(const float* __restrict__ eattr,
                                                        const float* __restrict__ st,
                                                        const int* __restrict__ ei,
                                                        int* __restrict__ cur,
                                                        uint4* __restrict__ bfh,
                                                        uint4* __restrict__ bfl,
                                                        uint4* __restrict__ b2f,
                                                        int* __restrict__ sperm) {
    const int e = blockIdx.x * 256 + threadIdx.x;
    if (e >= EE) return;
    const int tgt = ei[EE + e];
    const int p = atomicAdd(&cur[tgt], 1);
    sperm[p] = ei[e];
    float ea[16];
    {
        const float4* ep = (const float4*)(eattr + e * DEDGE);
#pragma unroll
        for (int c = 0; c < 4; ++c) {
            const float4 t4 = ep[c];
            ea[4 * c] = t4.x; ea[4 * c + 1] = t4.y; ea[4 * c + 2] = t4.z; ea[4 * c + 3] = t4.w;
        }
    }
    float m = st[288];
#pragma unroll
    for (int k = 0; k < 16; ++k) m = fmaf(st[256 + k], ea[k], m);
    float ex2 = st[289];
#pragma unroll
    for (int k = 0; k < 16; ++k) {
        float tv = 2.f * st[272 + k];
#pragma unroll
        for (int j = 0; j < 16; ++j) tv = fmaf(st[k * 16 + j], ea[j], tv);
        ex2 = fmaf(tv, ea[k], ex2);
    }
    const float var = fmaxf(ex2 - m * m, 0.f);
    const float inv = rsqrtf(var + 1e-5f);
    const float nmi = -m * inv;
    const int tt = p >> 5, col = p & 31;
#pragma unroll
    for (int h = 0; h < 2; ++h) {
        unsigned short uh[8], ul[8];
#pragma unroll
        for (int i = 0; i < 8; ++i) {
            const float v = inv * ea[8 * h + i];
            const unsigned short a = bf16rne(v);
            uh[i] = a;
            ul[i] = bf16rne(v - bf16tof(a));
        }
        bfh[tt * 64 + h * 32 + col] = pack8(uh);
        bfl[tt * 64 + h * 32 + col] = pack8(ul);
    }
    const unsigned short ivh = bf16rne(inv);
    const unsigned short ivl = bf16rne(inv - bf16tof(ivh));
    const unsigned short nmh = bf16rne(nmi);
    const unsigned short nml = bf16rne(nmi - bf16tof(nmh));
    const unsigned short one = 0x3F80;
    unsigned short s[8] = {ivh, ivh, ivl, nmh, nmh, nml, one, one};
    b2f[tt * 64 + col] = pack8(s);
    b2f[tt * 64 + 32 + col] = make_uint4(0, 0, 0, 0);
}

// ---------------- edge kernel v4: d-split wave pairs, 5000 waves, no occupancy hint ----------------
// 256 threads = 4 waves = 2 tile-groups x 2 d-halves. Group g computes tile b*2+g; sub s
// accumulates d in [16s,16s+16); partials combined via 8 KB LDS (conflict-free: lane-major).
// A/B-frags read directly from L2 (R5-proven adequate). No big LDS, no register hints.
__global__ __launch_bounds__(256) void edge_mfma_split(
    const float* __restrict__ x, const int* __restrict__ sperm,
    const uint4* __restrict__ afh, const uint4* __restrict__ afl, const uint4* __restrict__ a2f,
    const uint4* __restrict__ bfh, const uint4* __restrict__ bfl, const uint4* __restrict__ b2f,
    float* __restrict__ msgout) {
    __shared__ float pm[2][16 * 64];  // 8 KB
    const int t = threadIdx.x;
    const int wv = t >> 6, lane = t & 63;
    const int g = wv >> 1, s = wv & 1;
    const int col = lane & 31, hi2 = lane >> 5;
    const int w = blockIdx.x * 2 + g;  // grid = 1250 -> w in [0, 2500)
    const int p = w * 32 + col;
    const int si = sperm[p];

    float xr[16];
    {
        const float4* xp = (const float4*)(x + si * DD + s * 16);
#pragma unroll
        for (int c = 0; c < 4; ++c) {
            const float4 t4 = xp[c];
            xr[4 * c] = t4.x; xr[4 * c + 1] = t4.y; xr[4 * c + 2] = t4.z; xr[4 * c + 3] = t4.w;
        }
    }
    const short8v bh = ((const short8v*)bfh)[w * 64 + lane];
    const short8v bl = ((const short8v*)bfl)[w * 64 + lane];
    const short8v b2 = ((const short8v*)b2f)[w * 64 + lane];
    float mg[16];
#pragma unroll
    for (int i = 0; i < 16; ++i) mg[i] = 0.f;
#pragma unroll
    for (int dd = 0; dd < 16; ++dd) {
        const int d = s * 16 + dd;
        const short8v ah = ((const short8v*)afh)[d * 64 + lane];
        const short8v al = ((const short8v*)afl)[d * 64 + lane];
        const short8v a2 = ((const short8v*)a2f)[d * 64 + lane];
        f32x16 C;
#pragma unroll
        for (int r = 0; r < 16; ++r) C[r] = 0.f;
        C = __builtin_amdgcn_mfma_f32_32x32x16_bf16(ah, bh, C, 0, 0, 0);
        C = __builtin_amdgcn_mfma_f32_32x32x16_bf16(ah, bl, C, 0, 0, 0);
        C = __builtin_amdgcn_mfma_f32_32x32x16_bf16(al, bh, C, 0, 0, 0);
        C = __builtin_amdgcn_mfma_f32_32x32x16_bf16(a2, b2, C, 0, 0, 0);
        const float xd = xr[dd];
#pragma unroll
        for (int r = 0; r < 16; ++r) mg[r] = fmaf(xd, fmaxf(C[r], 0.f), mg[r]);
    }
    if (s == 1) {
#pragma unroll
        for (int r = 0; r < 16; ++r) pm[g][r * 64 + lane] = mg[r];
    }
    __syncthreads();
    if (s == 0) {
#pragma unroll
        for (int r = 0; r < 16; ++r) mg[r] += pm[g][r * 64 + lane];
        float* op = msgout + p * DD + hi2 * 4;
#pragma unroll
        for (int q = 0; q < 4; ++q)
            *(float4*)(op + q * 8) =
                make_float4(mg[4 * q], mg[4 * q + 1], mg[4 * q + 2], mg[4 * q + 3]);
    }
}

// ---------------- node update, sequential msg gather (layers 0,1) ----------------
__global__ __launch_bounds__(256) void node_wave_kernel(
    const float* __restrict__ x, const float* __restrict__ msg,
    const int* __restrict__ off,
    const float* __restrict__ root_w, const float* __restrict__ conv_b,
    const float* __restrict__ res_w, const float* __restrict__ res_b,
    const float* __restrict__ lng, const float* __restrict__ lnb,
    float* __restrict__ out) {
    const int lane = threadIdx.x & 63;
    const int w = (blockIdx.x * 256 + threadIdx.x) >> 6;  // 0..4999
    const int hi = lane >> 5, f = lane & 31;
    const int n = w * 2 + hi;
    float wrow[32];
    {
        const float4* rp = (const float4*)(root_w + f * DD);
        const float4* sp = (const float4*)(res_w + f * DD);
#pragma unroll
        for (int c = 0; c < 8; ++c) {
            const float4 a = rp[c];
            const float4 b = sp[c];
            wrow[4 * c] = a.x + b.x; wrow[4 * c + 1] = a.y + b.y;
            wrow[4 * c + 2] = a.z + b.z; wrow[4 * c + 3] = a.w + b.w;
        }
    }
    float acc = conv_b[f] + res_b[f];
    const int k0 = off[n], k1 = off[n + 1];
    for (int k = k0; k < k1; ++k) acc += msg[k * DD + f];
    const float xl = x[n * DD + f];
#pragma unroll
    for (int d = 0; d < DD; ++d) acc = fmaf(__shfl(xl, hi * 32 + d), wrow[d], acc);
    float s1 = acc, s2 = acc * acc;
#pragma unroll
    for (int o = 16; o >= 1; o >>= 1) {
        s1 += __shfl_xor(s1, o);
        s2 += __shfl_xor(s2, o);
    }
    const float m = s1 * (1.f / 32.f);
    const float v = s2 * (1.f / 32.f) - m * m;
    const float inv = rsqrtf(v + 1e-5f);
    out[n * DD + f] = fmaf((acc - m) * inv, lng[f], lnb[f]);
}

// ---------------- layer-2 node update fused with fusion head ----------------
__global__ __launch_bounds__(256) void node_fuse_kernel(
    const float* __restrict__ x, const float* __restrict__ msg,
    const int* __restrict__ off,
    const float* __restrict__ root_w, const float* __restrict__ conv_b,
    const float* __restrict__ res_w, const float* __restrict__ res_b,
    const float* __restrict__ lng, const float* __restrict__ lnb,
    const float* __restrict__ o0, const float* __restrict__ o1,
    const float* __restrict__ fw, const float* __restrict__ fb,
    const float* __restrict__ fg, const float* __restrict__ fbb,
    float* __restrict__ out) {
    const int lane = threadIdx.x & 63;
    const int w = (blockIdx.x * 256 + threadIdx.x) >> 6;
    const int hi = lane >> 5, f = lane & 31;
    const int n = w * 2 + hi;
    float o2v;
    {
        float wrow[32];
        {
            const float4* rp = (const float4*)(root_w + f * DD);
            const float4* sp = (const float4*)(res_w + f * DD);
#pragma unroll
            for (int c = 0; c < 8; ++c) {
                const float4 a = rp[c];
                const float4 b = sp[c];
                wrow[4 * c] = a.x + b.x; wrow[4 * c + 1] = a.y + b.y;
                wrow[4 * c + 2] = a.z + b.z; wrow[4 * c + 3] = a.w + b.w;
            }
        }
        float acc = conv_b[f] + res_b[f];
        const int k0 = off[n], k1 = off[n + 1];
        for (int k = k0; k < k1; ++k) acc += msg[k * DD + f];
        const float xl = x[n * DD + f];
#pragma unroll
        for (int d = 0; d < DD; ++d) acc = fmaf(__shfl(xl, hi * 32 + d), wrow[d], acc);
        float s1 = acc, s2 = acc * acc;
#pragma unroll
        for (int o = 16; o >= 1; o >>= 1) {
            s1 += __shfl_xor(s1, o);
            s2 += __shfl_xor(s2, o);
        }
        const float m = s1 * (1.f / 32.f);
        const float v = s2 * (1.f / 32.f) - m * m;
        const float inv = rsqrtf(v + 1e-5f);
        o2v = fmaf((acc - m) * inv, lng[f], lnb[f]);
    }
    float fr[96];
    {
        const float4* fp = (const float4*)(fw + f * 96);
#pragma unroll
        for (int c = 0; c < 24; ++c) {
            const float4 t4 = fp[c];
            fr[4 * c] = t4.x; fr[4 * c + 1] = t4.y; fr[4 * c + 2] = t4.z; fr[4 * c + 3] = t4.w;
        }
    }
    float acc = fb[f];
    const float c0 = o0[n * DD + f], c1 = o1[n * DD + f];
#pragma unroll
    for (int d = 0; d < DD; ++d) acc = fmaf(__shfl(c0, hi * 32 + d), fr[d], acc);
#pragma unroll
    for (int d = 0; d < DD; ++d) acc = fmaf(__shfl(c1, hi * 32 + d), fr[32 + d], acc);
#pragma unroll
    for (int d = 0; d < DD; ++d) acc = fmaf(__shfl(o2v, hi * 32 + d), fr[64 + d], acc);
    float s1 = acc, s2 = acc * acc;
#pragma unroll
    for (int o = 16; o >= 1; o >>= 1) {
        s1 += __shfl_xor(s1, o);
        s2 += __shfl_xor(s2, o);
    }
    const float m = s1 * (1.f / 32.f);
    const float v = s2 * (1.f / 32.f) - m * m;
    const float inv = rsqrtf(v + 1e-5f);
    out[n * DD + f] = fmaxf(fmaf((acc - m) * inv, fg[f], fbb[f]), 0.f);
}

extern "C" void kernel_launch(void* const* d_in, const int* in_sizes, int n_in,
                              void* d_out, int out_size, void* d_ws, size_t ws_size,
                              hipStream_t stream) {
    const float* x   = (const float*)d_in[0];
    const int*   ei  = (const int*)d_in[1];
    const float* ea  = (const float*)d_in[2];
    const float* emw = (const float*)d_in[3];
    const float* emb = (const float*)d_in[4];
    const float* elg = (const float*)d_in[5];
    const float* elb = (const float*)d_in[6];
    const float* rootw = (const float*)d_in[7];
    const float* convb = (const float*)d_in[8];
    const float* resw  = (const float*)d_in[9];
    const float* resb  = (const float*)d_in[10];
    const float* lng   = (const float*)d_in[11];
    const float* lnb   = (const float*)d_in[12];
    const float* fw    = (const float*)d_in[13];
    const float* fb    = (const float*)d_in[14];
    const float* flg   = (const float*)d_in[15];
    const float* flb   = (const float*)d_in[16];
    float* doutp = (float*)d_out;

    // layout: uint4 frags (afh|afl|a2f|bfh|bfl|b2f) | msg | out0 | out1 | st | cur | off | spare | sperm
    const size_t U4N = 2048 * 3 + (size_t)NTILE * 64 * 3;
    const size_t FR0 = U4N * 4;
    const size_t FTOT = FR0 + (size_t)EE * DD + 2 * (size_t)NN * DD + 320;
    const size_t ITOT = 2 * (NN + 1) + 2 * (size_t)EE;
    const size_t PRIMARY_NEED = FTOT * 4 + ITOT * 4 + 256;

    if (ws_size < PRIMARY_NEED) return;  // harness provides ample workspace

    uint4* u4 = (uint4*)d_ws;
    uint4* afh = u4;
    uint4* afl = afh + 2048;
    uint4* a2f = afl + 2048;
    uint4* bfh = a2f + 2048;
    uint4* bfl = bfh + (size_t)NTILE * 64;
    uint4* b2f = bfl + (size_t)NTILE * 64;
    float* wsf = (float*)d_ws;
    float* msg  = wsf + FR0;
    float* out0 = msg + (size_t)EE * DD;
    float* out1 = out0 + NN * DD;
    float* st   = out1 + NN * DD;
    int* cur   = (int*)(st + 320);
    int* off   = cur + (NN + 1);
    int* spare = off + (NN + 1);
    int* sperm = spare + EE;
    (void)spare;

    // R13-proven setup chain (4 dispatches)
    zero_kernel<<<41, 256, 0, stream>>>((int*)st, 320 + NN + 1);
    setup1_kernel<<<385, 256, 0, stream>>>(ei, emw, emb, elg, elb, cur, st, afh, afl, a2f);
    scan_kernel<<<1, 1024, 0, stream>>>(cur, off);
    stats_edge_perm2<<<313, 256, 0, stream>>>(ea, st, ei, cur, bfh, bfl, b2f, sperm);

    // layer 0
    edge_mfma_split<<<1250, 256, 0, stream>>>(x, sperm, afh, afl, a2f, bfh, bfl, b2f, msg);
    node_wave_kernel<<<1250, 256, 0, stream>>>(x, msg, off,
        rootw, convb, resw, resb, lng, lnb, out0);
    // layer 1
    edge_mfma_split<<<1250, 256, 0, stream>>>(out0, sperm, afh, afl, a2f, bfh, bfl, b2f, msg);
    node_wave_kernel<<<1250, 256, 0, stream>>>(out0, msg, off,
        rootw + D2V, convb + DD, resw + D2V, resb + DD, lng + DD, lnb + DD, out1);
    // layer 2 + fusion head
    edge_mfma_split<<<1250, 256, 0, stream>>>(out1, sperm, afh, afl, a2f, bfh, bfl, b2f, msg);
    node_fuse_kernel<<<1250, 256, 0, stream>>>(out1, msg, off,
        rootw + 2 * D2V, convb + 2 * DD, resw + 2 * D2V, resb + 2 * DD,
        lng + 2 * DD, lnb + 2 * DD,
        out0, out1, fw, fb, flg, flb, doutp);
}